// Round 18
// baseline (681.988 us; speedup 1.0000x reference)
//
#include <hip/hip_runtime.h>
#include <hip/hip_bf16.h>

#define M_TOT 8192
#define N_TOT 16384
#define K_TOT 4096
#define NT2 (K_TOT / 128)  // 32 K-tiles of BK=128

typedef int i32x4 __attribute__((ext_vector_type(4)));
typedef int i32x16 __attribute__((ext_vector_type(16)));
typedef __bf16 bf16x8 __attribute__((ext_vector_type(8)));
typedef float f32x4 __attribute__((ext_vector_type(4)));

#define GLOAD_LDS16(g, l)                                                     \
  __builtin_amdgcn_global_load_lds(                                           \
      (__attribute__((address_space(1))) const void*)(g),                     \
      (__attribute__((address_space(3))) void*)(l), 16, 0, 0)

__device__ __forceinline__ ushort f2bf_rne(float f) {
  unsigned u = __float_as_uint(f);
  u += 0x7FFFu + ((u >> 16) & 1u);
  return (ushort)(u >> 16);
}
__device__ __forceinline__ ushort sgn_bf16(float w) {
  return w > 0.f ? (ushort)0x3F80u : (w < 0.f ? (ushort)0xBF80u : (ushort)0u);
}

// ============ Fragment-order (tiled) operand layouts (R10-verified) =========
// A_tiled: 1KB chunk (r32, kt, ks) at (r32*128 + kt*2 + ks)*1024; lane l
//   holds A[r32*32 + (l&31)][kt*64 + ks*32 + (l>>5)*16 .. +16).  (33.5 MB)
// B_tiled: same with n32: (n32*128 + kt*2 + ks)*1024.  (67 MB)
// For BK=128 tile T, the 4 K-slices kk=0..3 of row-group r32 are chunks
// (r32*128 + 4T + kk) -> per-tile byte offset T<<12, contiguous 4KB.

// ---------------- pass 1a: per-row amax + quantize x -> A_tiled --------------
__global__ void quant_x_kernel(const float* __restrict__ x,
                               char* __restrict__ At, float* __restrict__ s) {
  int row = blockIdx.x;
  int tid = threadIdx.x;
  const float4* xr = (const float4*)(x + (size_t)row * K_TOT + tid * 16);
  float4 v[4];
  float amax = 0.f;
#pragma unroll
  for (int j = 0; j < 4; ++j) {
    v[j] = xr[j];
    amax = fmaxf(amax, fmaxf(fmaxf(fabsf(v[j].x), fabsf(v[j].y)),
                             fmaxf(fabsf(v[j].z), fabsf(v[j].w))));
  }
#pragma unroll
  for (int o = 32; o > 0; o >>= 1) amax = fmaxf(amax, __shfl_xor(amax, o));
  __shared__ float wmax[4];
  if ((tid & 63) == 0) wmax[tid >> 6] = amax;
  __syncthreads();
  amax = fmaxf(fmaxf(wmax[0], wmax[1]), fmaxf(wmax[2], wmax[3]));
  float inv = amax > 0.f ? 127.0f / amax : 0.f;
  if (tid == 0) s[row] = amax * (1.0f / 127.0f);
  int q[16];
#pragma unroll
  for (int j = 0; j < 4; ++j) {
    q[j * 4 + 0] = max(-127, min(127, __float2int_rn(v[j].x * inv)));
    q[j * 4 + 1] = max(-127, min(127, __float2int_rn(v[j].y * inv)));
    q[j * 4 + 2] = max(-127, min(127, __float2int_rn(v[j].z * inv)));
    q[j * 4 + 3] = max(-127, min(127, __float2int_rn(v[j].w * inv)));
  }
  int4 o4;
  int* op = (int*)&o4;
#pragma unroll
  for (int j = 0; j < 4; ++j)
    op[j] = (q[j * 4] & 255) | ((q[j * 4 + 1] & 255) << 8) |
            ((q[j * 4 + 2] & 255) << 16) | ((q[j * 4 + 3] & 255) << 24);
  int r32 = row >> 5, l31 = row & 31;
  int kt = tid >> 2, ks = (tid >> 1) & 1, hi = tid & 1;
  size_t dst = ((size_t)(r32 * 128 + kt * 2 + ks) << 10) + ((hi * 32 + l31) << 4);
  *(int4*)(At + dst) = o4;
}

// ---------------- pass 1b: W -> sign i8 in B_tiled ----------------
__global__ void quant_w_kernel(const float* __restrict__ w,
                               char* __restrict__ Bt) {
  int n32 = blockIdx.x;  // 512 blocks
  int t = threadIdx.x;
#pragma unroll 4
  for (int i = 0; i < 32; ++i) {
    int c = i * 256 + t;
    int kt = c >> 7, ks = (c >> 6) & 1, l = c & 63;
    int n = n32 * 32 + (l & 31);
    int k = kt * 64 + ks * 32 + (l >> 5) * 16;
    const float4* src = (const float4*)(w + (size_t)n * K_TOT + k);
    int4 o4;
    int* op = (int*)&o4;
#pragma unroll
    for (int j = 0; j < 4; ++j) {
      float4 v = src[j];
      int q0 = v.x > 0.f ? 1 : (v.x < 0.f ? -1 : 0);
      int q1 = v.y > 0.f ? 1 : (v.y < 0.f ? -1 : 0);
      int q2 = v.z > 0.f ? 1 : (v.z < 0.f ? -1 : 0);
      int q3 = v.w > 0.f ? 1 : (v.w < 0.f ? -1 : 0);
      op[j] = (q0 & 255) | ((q1 & 255) << 8) | ((q2 & 255) << 16) |
              ((q3 & 255) << 24);
    }
    *(int4*)(Bt + ((size_t)n32 << 17) + ((size_t)c << 4)) = o4;
  }
}

// ------ pass 2: i8 GEMM, 256x256 tile, BK=128, ONE barrier per 128-K --------
// C[m][n] = s[m]*(sum_k A8[m][k]*W8[n][k]) + bias[n]  (i32 accum, exact)
// R17 (543us, MfmaUtil 48) + sync-halving: 32 tiles of BK=128, 2 LDS bufs
// of 64KB (A 32KB | B 32KB) = 128KB, 1 block/CU, 2 waves/SIMD.
// X/Y fragment rotation over 4 ks-slices; 3 of 4 MFMA clusters overlap
// independent in-flight ds_reads; cluster ks3 completes BEFORE the barrier
// so ALL buf-b reads are lgkm-consumed pre-barrier (WAR-safe with 2 bufs:
// STAGE(t+1) targets b^1 only; fences pin motion at barriers — R13 lesson).
//   per tile t (b=t&1):
//     STAGE(t+1 -> b^1)  [8 gload_lds/thread]
//     Y<-(b,ks1); MFMA X[ks0]; X<-(b,ks2); MFMA Y[ks1];
//     Y<-(b,ks3); MFMA X[ks2]; MFMA Y[ks3];
//     vmcnt(0)  [STAGE(t+1), issued ~2300cyc ago -> stall-free]
//     fence; s_barrier; fence
//     X<-(t+1: b^1, ks0)
__global__ __launch_bounds__(512, 2) void gemm_i8_bk128(
    const char* __restrict__ At, const char* __restrict__ Bt,
    const float* __restrict__ s, const float* __restrict__ bias,
    float* __restrict__ C) {
  __shared__ char lds[2][65536];  // [buf][A 32KB | B 32KB]

  // XCD swizzle: 2048 blocks (32 bm x 64 bn); per XCD one bn stripe.
  int bid = blockIdx.x;
  int wg = (bid & 7) * 256 + (bid >> 3);
  int bnS = wg >> 8;
  int rem = wg & 255;
  int bm = rem >> 3;
  int bn = bnS * 8 + (rem & 7);
  int rowBase = bm * 256;
  int colBase = bn * 256;

  int t = threadIdx.x;
  int lane = t & 63;
  int wave = t >> 6;
  int wr = wave >> 2;  // 0..1 -> M half (128)
  int wc = wave & 3;   // 0..3 -> N quarter (64)
  int l31 = lane & 31;
  int hi = lane >> 5;

  // staging sources: per buf, A = 32 chunks of 1KB (g = r32l*4 + kk),
  // B same at +32KB. Thread t covers slots ss = t + 512q (q=0..3) for each
  // operand; src chunk = (bX*8 + (g>>2))*128 + (g&3), + T<<12 per tile.
  const char* gAp[4];
  const char* gBp[4];
#pragma unroll
  for (int q = 0; q < 4; ++q) {
    int ss = t + 512 * q;
    int g = ss >> 6;  // 8q .. 8q+7
    int r32l = g >> 2, kk = g & 3;
    int j = ss & 63;
    gAp[q] = At + ((size_t)((bm * 8 + r32l) * 128 + kk) << 10) + (j << 4);
    gBp[q] = Bt + ((size_t)((bn * 8 + r32l) * 128 + kk) << 10) + (j << 4);
  }

  i32x16 acc[4][2] = {};
  i32x4 Xa[4], Xb[2], Ya[4], Yb[2];  // two static fragment sets

#define STAGE(T_, buf_)                                                       \
  {                                                                           \
    size_t _o = (size_t)(T_) << 12;                                           \
    GLOAD_LDS16(gAp[0] + _o, &lds[buf_][t * 16]);                             \
    GLOAD_LDS16(gAp[1] + _o, &lds[buf_][8192 + t * 16]);                      \
    GLOAD_LDS16(gAp[2] + _o, &lds[buf_][16384 + t * 16]);                     \
    GLOAD_LDS16(gAp[3] + _o, &lds[buf_][24576 + t * 16]);                     \
    GLOAD_LDS16(gBp[0] + _o, &lds[buf_][32768 + t * 16]);                     \
    GLOAD_LDS16(gBp[1] + _o, &lds[buf_][40960 + t * 16]);                     \
    GLOAD_LDS16(gBp[2] + _o, &lds[buf_][49152 + t * 16]);                     \
    GLOAD_LDS16(gBp[3] + _o, &lds[buf_][57344 + t * 16]);                     \
  }
#define READF(Adst, Bdst, buf_, kq_)                                          \
  {                                                                           \
    const char* _la = &lds[buf_][0];                                          \
    const char* _lb = _la + 32768;                                            \
    _Pragma("unroll") for (int mi = 0; mi < 4; ++mi)                          \
        Adst[mi] = *(const i32x4*)(_la + (((wr * 4 + mi) * 4 + (kq_)) << 10) + \
                                   (lane << 4));                              \
    _Pragma("unroll") for (int ni = 0; ni < 2; ++ni)                          \
        Bdst[ni] = *(const i32x4*)(_lb + (((wc * 2 + ni) * 4 + (kq_)) << 10) + \
                                   (lane << 4));                              \
  }
#define MFMACL(Asrc, Bsrc)                                                    \
  {                                                                           \
    __builtin_amdgcn_s_setprio(1);                                            \
    _Pragma("unroll") for (int mi = 0; mi < 4; ++mi) {                        \
      acc[mi][0] = __builtin_amdgcn_mfma_i32_32x32x32_i8(Asrc[mi], Bsrc[0],   \
                                                         acc[mi][0], 0, 0, 0); \
      acc[mi][1] = __builtin_amdgcn_mfma_i32_32x32x32_i8(Asrc[mi], Bsrc[1],   \
                                                         acc[mi][1], 0, 0, 0); \
    }                                                                         \
    __builtin_amdgcn_s_setprio(0);                                            \
  }

  // prologue: tile 0 staged + collectively landed; X = (0,ks0)
  STAGE(0, 0);
  asm volatile("s_waitcnt vmcnt(0)" ::: "memory");
  __builtin_amdgcn_sched_barrier(0);
  __builtin_amdgcn_s_barrier();
  __builtin_amdgcn_sched_barrier(0);
  READF(Xa, Xb, 0, 0);

  for (int tt = 0; tt < NT2; ++tt) {
    int b = tt & 1;
    if (tt + 1 < NT2) STAGE(tt + 1, b ^ 1);
    READF(Ya, Yb, b, 1);  // ks1 — independent of MFMA below
    MFMACL(Xa, Xb);       // ks0
    READF(Xa, Xb, b, 2);  // ks2
    MFMACL(Ya, Yb);       // ks1
    READF(Ya, Yb, b, 3);  // ks3
    MFMACL(Xa, Xb);       // ks2
    MFMACL(Ya, Yb);       // ks3 — completes (lgkm-consumes Y) BEFORE barrier
    if (tt + 1 < NT2) {
      asm volatile("s_waitcnt vmcnt(0)" ::: "memory");  // STAGE(t+1), old
      __builtin_amdgcn_sched_barrier(0);
      __builtin_amdgcn_s_barrier();  // collective: buf b^1 fully written
      __builtin_amdgcn_sched_barrier(0);
      READF(Xa, Xb, b ^ 1, 0);  // (t+1, ks0) — overlaps next tile's MFMA
    }
  }

#undef MFMACL
#undef READF
#undef STAGE

  // epilogue: y = s[m] * acc + bias[n]
  // C/D 32x32: col = lane&31, row = (reg&3) + 8*(reg>>2) + 4*(lane>>5)
#pragma unroll
  for (int mi = 0; mi < 4; ++mi) {
#pragma unroll
    for (int ni = 0; ni < 2; ++ni) {
      int gc = colBase + wc * 64 + ni * 32 + l31;
      float bv = bias[gc];
#pragma unroll
      for (int rg = 0; rg < 16; ++rg) {
        int rowIn = (rg & 3) + 8 * (rg >> 2) + 4 * hi;
        int gr = rowBase + wr * 128 + mi * 32 + rowIn;
        C[(size_t)gr * N_TOT + gc] = (float)acc[mi][ni][rg] * s[gr] + bv;
      }
    }
  }
}

// ---------------- fallback (ws too small): fused bf16 conversion GEMM --------
__global__ void gemm_fused_kernel(const float* __restrict__ A,
                                  const float* __restrict__ W,
                                  const float* __restrict__ bias,
                                  float* __restrict__ C) {
  __shared__ ushort lsA[128 * 32];
  __shared__ ushort lsB[128 * 32];

  int nwg = gridDim.x;
  int bid = blockIdx.x;
  int wg = (bid & 7) * (nwg >> 3) + (bid >> 3);
  const int NBN = N_TOT / 128;
  int bm = wg / NBN;
  int bn = wg % NBN;
  int rowBase = bm * 128;
  int colBase = bn * 128;

  int t = threadIdx.x;
  int lane = t & 63;
  int wave = t >> 6;
  int wm = (wave >> 1) * 64;
  int wn = (wave & 1) * 64;

  f32x4 acc[4][4] = {};

  int srow = t >> 3;
  int scol = (t & 7) * 4;
  int fr = lane & 15;
  int koff = (lane >> 4) * 8;

  for (int k0 = 0; k0 < K_TOT; k0 += 32) {
    float4 va[4], vb[4];
#pragma unroll
    for (int r = 0; r < 4; ++r) {
      va[r] = *(const float4*)&A[(size_t)(rowBase + r * 32 + srow) * K_TOT + k0 + scol];
      vb[r] = *(const float4*)&W[(size_t)(colBase + r * 32 + srow) * K_TOT + k0 + scol];
    }
    __syncthreads();
#pragma unroll
    for (int r = 0; r < 4; ++r) {
      int e = r * 1024 + t * 4;
      ushort4 oa, ob;
      oa.x = f2bf_rne(va[r].x); oa.y = f2bf_rne(va[r].y);
      oa.z = f2bf_rne(va[r].z); oa.w = f2bf_rne(va[r].w);
      ob.x = sgn_bf16(vb[r].x); ob.y = sgn_bf16(vb[r].y);
      ob.z = sgn_bf16(vb[r].z); ob.w = sgn_bf16(vb[r].w);
      *(ushort4*)&lsA[e] = oa;
      *(ushort4*)&lsB[e] = ob;
    }
    __syncthreads();

    bf16x8 af[4], bfr[4];
#pragma unroll
    for (int i = 0; i < 4; ++i)
      af[i] = *(const bf16x8*)&lsA[(wm + i * 16 + fr) * 32 + koff];
#pragma unroll
    for (int j = 0; j < 4; ++j)
      bfr[j] = *(const bf16x8*)&lsB[(wn + j * 16 + fr) * 32 + koff];

#pragma unroll
    for (int i = 0; i < 4; ++i)
#pragma unroll
      for (int j = 0; j < 4; ++j)
        acc[i][j] = __builtin_amdgcn_mfma_f32_16x16x32_bf16(af[i], bfr[j],
                                                            acc[i][j], 0, 0, 0);
  }

  int orow0 = rowBase + wm + ((lane >> 4) << 2);
  int ocol0 = colBase + wn + (lane & 15);
#pragma unroll
  for (int i = 0; i < 4; ++i) {
#pragma unroll
    for (int j = 0; j < 4; ++j) {
      int col = ocol0 + j * 16;
      float bv = bias[col];
#pragma unroll
      for (int rg = 0; rg < 4; ++rg) {
        int row = orow0 + i * 16 + rg;
        C[(size_t)row * N_TOT + col] = acc[i][j][rg] + bv;
      }
    }
  }
}

extern "C" void kernel_launch(void* const* d_in, const int* in_sizes, int n_in,
                              void* d_out, int out_size, void* d_ws,
                              size_t ws_size, hipStream_t stream) {
  const float* x = (const float*)d_in[0];
  const float* W = (const float*)d_in[1];
  const float* b = (const float*)d_in[2];
  float* out = (float*)d_out;

  const size_t xq_bytes = (size_t)M_TOT * K_TOT;           // 33.5 MB
  const size_t wq_bytes = (size_t)N_TOT * K_TOT;           // 67.1 MB
  const size_t need = xq_bytes + wq_bytes + M_TOT * 4;     // ~101 MB

  if (ws_size >= need) {
    char* At = (char*)d_ws;
    char* Bt = At + xq_bytes;
    float* s = (float*)(Bt + wq_bytes);
    quant_x_kernel<<<M_TOT, 256, 0, stream>>>(x, At, s);
    quant_w_kernel<<<N_TOT / 32, 256, 0, stream>>>(W, Bt);
    const int nblocks = (M_TOT / 256) * (N_TOT / 256);  // 2048
    gemm_i8_bk128<<<nblocks, 512, 0, stream>>>(At, Bt, s, b, out);
  } else {
    const int nblocks = (M_TOT / 128) * (N_TOT / 128);
    gemm_fused_kernel<<<nblocks, 256, 0, stream>>>(x, W, b, out);
  }
}

// Round 19
// 654.433 us; speedup vs baseline: 1.0421x; 1.0421x over previous
//
#include <hip/hip_runtime.h>
#include <hip/hip_bf16.h>

#define M_TOT 8192
#define N_TOT 16384
#define K_TOT 4096
#define NT (K_TOT / 64)  // 64 K-tiles of BK=64

typedef int i32x4 __attribute__((ext_vector_type(4)));
typedef int i32x16 __attribute__((ext_vector_type(16)));
typedef __bf16 bf16x8 __attribute__((ext_vector_type(8)));
typedef float f32x4 __attribute__((ext_vector_type(4)));

#define GLOAD_LDS16(g, l)                                                     \
  __builtin_amdgcn_global_load_lds(                                           \
      (__attribute__((address_space(1))) const void*)(g),                     \
      (__attribute__((address_space(3))) void*)(l), 16, 0, 0)

__device__ __forceinline__ ushort f2bf_rne(float f) {
  unsigned u = __float_as_uint(f);
  u += 0x7FFFu + ((u >> 16) & 1u);
  return (ushort)(u >> 16);
}
__device__ __forceinline__ ushort sgn_bf16(float w) {
  return w > 0.f ? (ushort)0x3F80u : (w < 0.f ? (ushort)0xBF80u : (ushort)0u);
}

// ============ Fragment-order (tiled) operand layouts (R10-verified) =========
// A_tiled: 1KB chunk (r32, kt, ks) at (r32*128 + kt*2 + ks)*1024; lane l
//   holds A[r32*32 + (l&31)][kt*64 + ks*32 + (l>>5)*16 .. +16).  (33.5 MB)
// B_tiled: same with n32: (n32*128 + kt*2 + ks)*1024.  (67 MB)

// ---------------- pass 1a: per-row amax + quantize x -> A_tiled --------------
__global__ void quant_x_kernel(const float* __restrict__ x,
                               char* __restrict__ At, float* __restrict__ s) {
  int row = blockIdx.x;
  int tid = threadIdx.x;
  const float4* xr = (const float4*)(x + (size_t)row * K_TOT + tid * 16);
  float4 v[4];
  float amax = 0.f;
#pragma unroll
  for (int j = 0; j < 4; ++j) {
    v[j] = xr[j];
    amax = fmaxf(amax, fmaxf(fmaxf(fabsf(v[j].x), fabsf(v[j].y)),
                             fmaxf(fabsf(v[j].z), fabsf(v[j].w))));
  }
#pragma unroll
  for (int o = 32; o > 0; o >>= 1) amax = fmaxf(amax, __shfl_xor(amax, o));
  __shared__ float wmax[4];
  if ((tid & 63) == 0) wmax[tid >> 6] = amax;
  __syncthreads();
  amax = fmaxf(fmaxf(wmax[0], wmax[1]), fmaxf(wmax[2], wmax[3]));
  float inv = amax > 0.f ? 127.0f / amax : 0.f;
  if (tid == 0) s[row] = amax * (1.0f / 127.0f);
  int q[16];
#pragma unroll
  for (int j = 0; j < 4; ++j) {
    q[j * 4 + 0] = max(-127, min(127, __float2int_rn(v[j].x * inv)));
    q[j * 4 + 1] = max(-127, min(127, __float2int_rn(v[j].y * inv)));
    q[j * 4 + 2] = max(-127, min(127, __float2int_rn(v[j].z * inv)));
    q[j * 4 + 3] = max(-127, min(127, __float2int_rn(v[j].w * inv)));
  }
  int4 o4;
  int* op = (int*)&o4;
#pragma unroll
  for (int j = 0; j < 4; ++j)
    op[j] = (q[j * 4] & 255) | ((q[j * 4 + 1] & 255) << 8) |
            ((q[j * 4 + 2] & 255) << 16) | ((q[j * 4 + 3] & 255) << 24);
  int r32 = row >> 5, l31 = row & 31;
  int kt = tid >> 2, ks = (tid >> 1) & 1, hi = tid & 1;
  size_t dst = ((size_t)(r32 * 128 + kt * 2 + ks) << 10) + ((hi * 32 + l31) << 4);
  *(int4*)(At + dst) = o4;
}

// ---------------- pass 1b: W -> sign i8 in B_tiled ----------------
__global__ void quant_w_kernel(const float* __restrict__ w,
                               char* __restrict__ Bt) {
  int n32 = blockIdx.x;  // 512 blocks
  int t = threadIdx.x;
#pragma unroll 4
  for (int i = 0; i < 32; ++i) {
    int c = i * 256 + t;
    int kt = c >> 7, ks = (c >> 6) & 1, l = c & 63;
    int n = n32 * 32 + (l & 31);
    int k = kt * 64 + ks * 32 + (l >> 5) * 16;
    const float4* src = (const float4*)(w + (size_t)n * K_TOT + k);
    int4 o4;
    int* op = (int*)&o4;
#pragma unroll
    for (int j = 0; j < 4; ++j) {
      float4 v = src[j];
      int q0 = v.x > 0.f ? 1 : (v.x < 0.f ? -1 : 0);
      int q1 = v.y > 0.f ? 1 : (v.y < 0.f ? -1 : 0);
      int q2 = v.z > 0.f ? 1 : (v.z < 0.f ? -1 : 0);
      int q3 = v.w > 0.f ? 1 : (v.w < 0.f ? -1 : 0);
      op[j] = (q0 & 255) | ((q1 & 255) << 8) | ((q2 & 255) << 16) |
              ((q3 & 255) << 24);
    }
    *(int4*)(Bt + ((size_t)n32 << 17) + ((size_t)c << 4)) = o4;
  }
}

// ------ pass 2: i8 GEMM, 256x256 tile, cross-barrier pipeline (R17-best) ----
// C[m][n] = s[m]*(sum_k A8[m][k]*W8[n][k]) + bias[n]  (i32 accum, exact)
// R17 config VERBATIM (best measured: 543us GEMM, MfmaUtil 48.3) + unroll-4
// so the LDS buffer index is compile-time static (no runtime LDS base calc).
// 512 thr = 8 waves (2M x 4N), wave 128x64 (4mi x 2ni, acc 128 AGPR),
// LDS 4 bufs x 32KB = 128KB, 1 block/CU, 2 waves/SIMD.
//   per tile t (static buf=t&3):
//     STAGE(t+2 -> (t+2)&3) [4 gload_lds]
//     READ (t,ks1) -> Y  ||  MFMA X (t,ks0)
//     vmcnt(4)  [FIFO: STAGE(t+1) 4 + STAGE(t+2) 4 = 8 -> drains STAGE(t+1)]
//     fence; s_barrier; fence   [collective: buf(t+1) fully written]
//     READ (t+1,ks0) -> X  ||  MFMA Y (t,ks1)
// WAR: STAGE(t+2) rewrites buf(t-2); its last reads lgkm-consumed 2 barriers
// ago; fences pin all motion at barriers (R13 lesson).
__global__ __launch_bounds__(512, 2) void gemm_i8_pipe4(
    const char* __restrict__ At, const char* __restrict__ Bt,
    const float* __restrict__ s, const float* __restrict__ bias,
    float* __restrict__ C) {
  __shared__ char lds[4][32768];  // [buf][A 16KB | B 16KB]

  // XCD swizzle: 2048 blocks (32 bm x 64 bn); per XCD one bn stripe.
  int bid = blockIdx.x;
  int wg = (bid & 7) * 256 + (bid >> 3);
  int bnS = wg >> 8;
  int rem = wg & 255;
  int bm = rem >> 3;
  int bn = bnS * 8 + (rem & 7);
  int rowBase = bm * 256;
  int colBase = bn * 256;

  int t = threadIdx.x;
  int lane = t & 63;
  int wave = t >> 6;
  int wr = wave >> 2;  // 0..1 -> M half (128)
  int wc = wave & 3;   // 0..3 -> N quarter (64)
  int l31 = lane & 31;
  int hi = lane >> 5;

  const char* gAp[2];
  const char* gBp[2];
#pragma unroll
  for (int q = 0; q < 2; ++q) {
    int ss = t + 512 * q;
    int g = ss >> 6;
    int r32l = g >> 1, ks = g & 1;
    int j = ss & 63;
    gAp[q] = At + ((size_t)((bm * 8 + r32l) * 128 + ks) << 10) + (j << 4);
    gBp[q] = Bt + ((size_t)((bn * 8 + r32l) * 128 + ks) << 10) + (j << 4);
  }

  i32x16 acc[4][2] = {};
  i32x4 Xa[4], Xb[2], Ya[4], Yb[2];  // two static fragment sets

#define STAGE(kt_, buf_)                                                      \
  {                                                                           \
    size_t _o = (size_t)(kt_) << 11;                                          \
    GLOAD_LDS16(gAp[0] + _o, &lds[buf_][t * 16]);                             \
    GLOAD_LDS16(gAp[1] + _o, &lds[buf_][8192 + t * 16]);                      \
    GLOAD_LDS16(gBp[0] + _o, &lds[buf_][16384 + t * 16]);                     \
    GLOAD_LDS16(gBp[1] + _o, &lds[buf_][24576 + t * 16]);                     \
  }
#define READF(Adst, Bdst, buf_, ks_)                                          \
  {                                                                           \
    const char* _la = &lds[buf_][0];                                          \
    const char* _lb = _la + 16384;                                            \
    _Pragma("unroll") for (int mi = 0; mi < 4; ++mi)                          \
        Adst[mi] = *(const i32x4*)(_la + (((wr * 4 + mi) * 2 + (ks_)) << 10) + \
                                   (lane << 4));                              \
    _Pragma("unroll") for (int ni = 0; ni < 2; ++ni)                          \
        Bdst[ni] = *(const i32x4*)(_lb + (((wc * 2 + ni) * 2 + (ks_)) << 10) + \
                                   (lane << 4));                              \
  }
#define MFMACL(Asrc, Bsrc)                                                    \
  {                                                                           \
    __builtin_amdgcn_s_setprio(1);                                            \
    _Pragma("unroll") for (int mi = 0; mi < 4; ++mi) {                        \
      acc[mi][0] = __builtin_amdgcn_mfma_i32_32x32x32_i8(Asrc[mi], Bsrc[0],   \
                                                         acc[mi][0], 0, 0, 0); \
      acc[mi][1] = __builtin_amdgcn_mfma_i32_32x32x32_i8(Asrc[mi], Bsrc[1],   \
                                                         acc[mi][1], 0, 0, 0); \
    }                                                                         \
    __builtin_amdgcn_s_setprio(0);                                            \
  }
#define FENCED_BARRIER()                                                      \
  __builtin_amdgcn_sched_barrier(0);                                          \
  __builtin_amdgcn_s_barrier();                                               \
  __builtin_amdgcn_sched_barrier(0);
// full-pipeline tile: static buf index, vmcnt(4) drains STAGE(t+1)
#define TILE_FULL(tt_, buf_)                                                  \
  {                                                                           \
    STAGE((tt_) + 2, ((buf_) + 2) & 3);                                       \
    READF(Ya, Yb, buf_, 1);                                                   \
    MFMACL(Xa, Xb);                                                           \
    asm volatile("s_waitcnt vmcnt(4)" ::: "memory");                          \
    FENCED_BARRIER();                                                         \
    READF(Xa, Xb, ((buf_) + 1) & 3, 0);                                       \
    MFMACL(Ya, Yb);                                                           \
  }

  // prologue: tiles 0,1 staged; vmcnt(4) drains STAGE(0) (8 outstanding);
  // barrier -> buf0 collectively landed; X = (0,ks0)
  STAGE(0, 0);
  STAGE(1, 1);
  asm volatile("s_waitcnt vmcnt(4)" ::: "memory");
  FENCED_BARRIER();
  READF(Xa, Xb, 0, 0);

  // main: tiles 0..59 (15 x unroll-4, static bufs; staging reaches tile 61)
  for (int uo = 0; uo < 15; ++uo) {
    int kt = uo * 4;
    TILE_FULL(kt + 0, 0);
    TILE_FULL(kt + 1, 1);
    TILE_FULL(kt + 2, 2);
    TILE_FULL(kt + 3, 3);
  }
  // tail: tiles 60..63 (vmcnt counts audited: 8->4, 8->4, 4->0, none)
  {
    // tt=60, buf 0
    STAGE(62, 2);
    READF(Ya, Yb, 0, 1);
    MFMACL(Xa, Xb);
    asm volatile("s_waitcnt vmcnt(4)" ::: "memory");  // drains STAGE(61)
    FENCED_BARRIER();
    READF(Xa, Xb, 1, 0);
    MFMACL(Ya, Yb);
    // tt=61, buf 1
    STAGE(63, 3);
    READF(Ya, Yb, 1, 1);
    MFMACL(Xa, Xb);
    asm volatile("s_waitcnt vmcnt(4)" ::: "memory");  // drains STAGE(62)
    FENCED_BARRIER();
    READF(Xa, Xb, 2, 0);
    MFMACL(Ya, Yb);
    // tt=62, buf 2
    READF(Ya, Yb, 2, 1);
    MFMACL(Xa, Xb);
    asm volatile("s_waitcnt vmcnt(0)" ::: "memory");  // drains STAGE(63)
    FENCED_BARRIER();
    READF(Xa, Xb, 3, 0);
    MFMACL(Ya, Yb);
    // tt=63, buf 3
    READF(Ya, Yb, 3, 1);
    MFMACL(Xa, Xb);
    MFMACL(Ya, Yb);
  }

#undef TILE_FULL
#undef FENCED_BARRIER
#undef MFMACL
#undef READF
#undef STAGE

  // epilogue: y = s[m] * acc + bias[n]
  // C/D 32x32: col = lane&31, row = (reg&3) + 8*(reg>>2) + 4*(lane>>5)
#pragma unroll
  for (int mi = 0; mi < 4; ++mi) {
#pragma unroll
    for (int ni = 0; ni < 2; ++ni) {
      int gc = colBase + wc * 64 + ni * 32 + l31;
      float bv = bias[gc];
#pragma unroll
      for (int rg = 0; rg < 16; ++rg) {
        int rowIn = (rg & 3) + 8 * (rg >> 2) + 4 * hi;
        int gr = rowBase + wr * 128 + mi * 32 + rowIn;
        C[(size_t)gr * N_TOT + gc] = (float)acc[mi][ni][rg] * s[gr] + bv;
      }
    }
  }
}

// ---------------- fallback (ws too small): fused bf16 conversion GEMM --------
__global__ void gemm_fused_kernel(const float* __restrict__ A,
                                  const float* __restrict__ W,
                                  const float* __restrict__ bias,
                                  float* __restrict__ C) {
  __shared__ ushort lsA[128 * 32];
  __shared__ ushort lsB[128 * 32];

  int nwg = gridDim.x;
  int bid = blockIdx.x;
  int wg = (bid & 7) * (nwg >> 3) + (bid >> 3);
  const int NBN = N_TOT / 128;
  int bm = wg / NBN;
  int bn = wg % NBN;
  int rowBase = bm * 128;
  int colBase = bn * 128;

  int t = threadIdx.x;
  int lane = t & 63;
  int wave = t >> 6;
  int wm = (wave >> 1) * 64;
  int wn = (wave & 1) * 64;

  f32x4 acc[4][4] = {};

  int srow = t >> 3;
  int scol = (t & 7) * 4;
  int fr = lane & 15;
  int koff = (lane >> 4) * 8;

  for (int k0 = 0; k0 < K_TOT; k0 += 32) {
    float4 va[4], vb[4];
#pragma unroll
    for (int r = 0; r < 4; ++r) {
      va[r] = *(const float4*)&A[(size_t)(rowBase + r * 32 + srow) * K_TOT + k0 + scol];
      vb[r] = *(const float4*)&W[(size_t)(colBase + r * 32 + srow) * K_TOT + k0 + scol];
    }
    __syncthreads();
#pragma unroll
    for (int r = 0; r < 4; ++r) {
      int e = r * 1024 + t * 4;
      ushort4 oa, ob;
      oa.x = f2bf_rne(va[r].x); oa.y = f2bf_rne(va[r].y);
      oa.z = f2bf_rne(va[r].z); oa.w = f2bf_rne(va[r].w);
      ob.x = sgn_bf16(vb[r].x); ob.y = sgn_bf16(vb[r].y);
      ob.z = sgn_bf16(vb[r].z); ob.w = sgn_bf16(vb[r].w);
      *(ushort4*)&lsA[e] = oa;
      *(ushort4*)&lsB[e] = ob;
    }
    __syncthreads();

    bf16x8 af[4], bfr[4];
#pragma unroll
    for (int i = 0; i < 4; ++i)
      af[i] = *(const bf16x8*)&lsA[(wm + i * 16 + fr) * 32 + koff];
#pragma unroll
    for (int j = 0; j < 4; ++j)
      bfr[j] = *(const bf16x8*)&lsB[(wn + j * 16 + fr) * 32 + koff];

#pragma unroll
    for (int i = 0; i < 4; ++i)
#pragma unroll
      for (int j = 0; j < 4; ++j)
        acc[i][j] = __builtin_amdgcn_mfma_f32_16x16x32_bf16(af[i], bfr[j],
                                                            acc[i][j], 0, 0, 0);
  }

  int orow0 = rowBase + wm + ((lane >> 4) << 2);
  int ocol0 = colBase + wn + (lane & 15);
#pragma unroll
  for (int i = 0; i < 4; ++i) {
#pragma unroll
    for (int j = 0; j < 4; ++j) {
      int col = ocol0 + j * 16;
      float bv = bias[col];
#pragma unroll
      for (int rg = 0; rg < 4; ++rg) {
        int row = orow0 + i * 16 + rg;
        C[(size_t)row * N_TOT + col] = acc[i][j][rg] + bv;
      }
    }
  }
}

extern "C" void kernel_launch(void* const* d_in, const int* in_sizes, int n_in,
                              void* d_out, int out_size, void* d_ws,
                              size_t ws_size, hipStream_t stream) {
  const float* x = (const float*)d_in[0];
  const float* W = (const float*)d_in[1];
  const float* b = (const float*)d_in[2];
  float* out = (float*)d_out;

  const size_t xq_bytes = (size_t)M_TOT * K_TOT;           // 33.5 MB
  const size_t wq_bytes = (size_t)N_TOT * K_TOT;           // 67.1 MB
  const size_t need = xq_bytes + wq_bytes + M_TOT * 4;     // ~101 MB

  if (ws_size >= need) {
    char* At = (char*)d_ws;
    char* Bt = At + xq_bytes;
    float* s = (float*)(Bt + wq_bytes);
    quant_x_kernel<<<M_TOT, 256, 0, stream>>>(x, At, s);
    quant_w_kernel<<<N_TOT / 32, 256, 0, stream>>>(W, Bt);
    const int nblocks = (M_TOT / 256) * (N_TOT / 256);  // 2048
    gemm_i8_pipe4<<<nblocks, 512, 0, stream>>>(At, Bt, s, b, out);
  } else {
    const int nblocks = (M_TOT / 128) * (N_TOT / 128);
    gemm_fused_kernel<<<nblocks, 256, 0, stream>>>(x, W, b, out);
  }
}